// Round 7
// baseline (765.165 us; speedup 1.0000x reference)
//
#include <hip/hip_runtime.h>
#include <hip/hip_bf16.h>

#define N_NODES 30000
#define N_EDGES 480000
#define DIM 512
#define NREL 4
#define NSEG (NREL * N_NODES)   // 120000
#define KTOT ((NREL + 1) * DIM) // 2560
#define NT (KTOT / 64)          // 40 K-tiles of 64
#define NBM ((N_NODES + 255) / 256)  // 118
#define NWG_GEMM (NBM * 2)           // 236

typedef __attribute__((ext_vector_type(8))) short short8;
typedef __attribute__((ext_vector_type(4))) float f32x4;

__device__ __forceinline__ float bf2f(unsigned int hi) {
    union { unsigned int u; float f; } v; v.u = hi << 16; return v.f;
}
__device__ __forceinline__ unsigned short f2bf(float f) {
    union { float f; unsigned int u; } v; v.f = f;
    unsigned int u = v.u;
    unsigned int r = (u + 0x7fffu + ((u >> 16) & 1u)) >> 16;
    return (unsigned short)r;
}

// -------- prep: WcatT build for ALL 3 layers (B^T layout: [e][k]) in one launch ------
__global__ void k_wcat3(const float* __restrict__ W0, const float* __restrict__ r0,
                        const float* __restrict__ W1, const float* __restrict__ r1,
                        const float* __restrict__ W2, const float* __restrict__ r2,
                        unsigned short* __restrict__ wt) {
    int l = blockIdx.y;
    const float* W    = (l == 0) ? W0 : (l == 1) ? W1 : W2;
    const float* root = (l == 0) ? r0 : (l == 1) ? r1 : r2;
    unsigned short* o = wt + (size_t)l * DIM * KTOT;
    int i = blockIdx.x * 256 + threadIdx.x;       // over 512*2560, k fastest
    if (i >= DIM * KTOT) return;
    int k = i % KTOT, e = i / KTOT;
    float v;
    if (k < DIM) {
        v = root[k * DIM + e];
    } else {
        int kk = k - DIM;
        int r = kk >> 9; kk &= 511;
        v = W[(size_t)r * DIM * DIM + (size_t)kk * DIM + e];
    }
    o[(size_t)e * KTOT + k] = f2bf(v);
}

// ---------------- prep: x0 = emb[x_idx] (bf16 only) ----------------
__global__ void k_embed(const int* __restrict__ xidx, const float* __restrict__ emb,
                        unsigned short* __restrict__ xb) {
    int n = blockIdx.x;           // 30000
    int l = threadIdx.x;          // 64
    int id = xidx[n];
    const float4* er = (const float4*)(emb + (size_t)id * DIM + l * 8);
    float4 a = er[0], b = er[1];
    ushort4 pa, pb;
    pa.x = f2bf(a.x); pa.y = f2bf(a.y); pa.z = f2bf(a.z); pa.w = f2bf(a.w);
    pb.x = f2bf(b.x); pb.y = f2bf(b.y); pb.z = f2bf(b.z); pb.w = f2bf(b.w);
    ushort4* xbo = (ushort4*)(xb + (size_t)n * DIM + l * 8);
    xbo[0] = pa; xbo[1] = pb;
}

// ---------------- counting sort of edges by seg = etype*N + dst ----------------
__global__ void k_hist(const int* __restrict__ etype, const int* __restrict__ dst,
                       int* __restrict__ hist) {
    int e = blockIdx.x * 256 + threadIdx.x;
    if (e < N_EDGES) atomicAdd(&hist[etype[e] * N_NODES + dst[e]], 1);
}

__global__ void k_scan1(const int* __restrict__ hist, int* __restrict__ offsets,
                        int* __restrict__ bsums) {
    __shared__ int sdata[256];
    int t = threadIdx.x, b = blockIdx.x;
    int base = b * 2048 + t * 8;
    int v[8]; int s = 0;
    #pragma unroll
    for (int i = 0; i < 8; i++) {
        int idx = base + i;
        v[i] = (idx < NSEG) ? hist[idx] : 0;
        s += v[i];
    }
    sdata[t] = s; __syncthreads();
    for (int off = 1; off < 256; off <<= 1) {
        int x = (t >= off) ? sdata[t - off] : 0;
        __syncthreads();
        sdata[t] += x;
        __syncthreads();
    }
    int run = (t == 0) ? 0 : sdata[t - 1];
    #pragma unroll
    for (int i = 0; i < 8; i++) {
        run += v[i];
        int idx = base + i;
        if (idx < NSEG) offsets[idx + 1] = run;
    }
    if (t == 255) bsums[b] = sdata[255];
}

__global__ void k_scan2(int* __restrict__ bsums, int nb) {
    if (threadIdx.x == 0 && blockIdx.x == 0) {
        int run = 0;
        for (int i = 0; i < nb; i++) { int v = bsums[i]; bsums[i] = run; run += v; }
    }
}

__global__ void k_scan3(const int* __restrict__ bsums, int* __restrict__ offsets) {
    int t = threadIdx.x, b = blockIdx.x;
    int base = b * 2048 + t * 8;
    int add = bsums[b];
    #pragma unroll
    for (int i = 0; i < 8; i++) {
        int idx = base + i;
        if (idx < NSEG) offsets[idx + 1] += add;
    }
    if (b == 0 && t == 0) offsets[0] = 0;
}

__global__ void k_scatter(const int* __restrict__ etype, const int* __restrict__ src,
                          const int* __restrict__ dst, const int* __restrict__ offsets,
                          int* __restrict__ cursor, int* __restrict__ ssrc) {
    int e = blockIdx.x * 256 + threadIdx.x;
    if (e < N_EDGES) {
        int seg = etype[e] * N_NODES + dst[e];
        int p = atomicAdd(&cursor[seg], 1);
        ssrc[offsets[seg] + p] = src[e];
    }
}

// ---------------- per-layer segment-mean (reads bf16 x, writes bf16 mean) ----------------
__global__ __launch_bounds__(256) void k_agg(const unsigned short* __restrict__ xb,
                                             const int* __restrict__ ssrc,
                                             const int* __restrict__ offsets,
                                             unsigned short* __restrict__ meanb) {
    int wid = threadIdx.x >> 6, lane = threadIdx.x & 63;
    int seg = blockIdx.x * 4 + wid;
    int st = offsets[seg], en = offsets[seg + 1];
    float acc[8] = {0, 0, 0, 0, 0, 0, 0, 0};
    int i = st;
    for (; i + 1 < en; i += 2) {
        int s0 = ssrc[i], s1 = ssrc[i + 1];
        uint4 v0 = *(const uint4*)(xb + (size_t)s0 * DIM + lane * 8);
        uint4 v1 = *(const uint4*)(xb + (size_t)s1 * DIM + lane * 8);
        acc[0] += bf2f(v0.x & 0xffffu) + bf2f(v1.x & 0xffffu);
        acc[1] += bf2f(v0.x >> 16)     + bf2f(v1.x >> 16);
        acc[2] += bf2f(v0.y & 0xffffu) + bf2f(v1.y & 0xffffu);
        acc[3] += bf2f(v0.y >> 16)     + bf2f(v1.y >> 16);
        acc[4] += bf2f(v0.z & 0xffffu) + bf2f(v1.z & 0xffffu);
        acc[5] += bf2f(v0.z >> 16)     + bf2f(v1.z >> 16);
        acc[6] += bf2f(v0.w & 0xffffu) + bf2f(v1.w & 0xffffu);
        acc[7] += bf2f(v0.w >> 16)     + bf2f(v1.w >> 16);
    }
    if (i < en) {
        int s = ssrc[i];
        uint4 v = *(const uint4*)(xb + (size_t)s * DIM + lane * 8);
        acc[0] += bf2f(v.x & 0xffffu); acc[1] += bf2f(v.x >> 16);
        acc[2] += bf2f(v.y & 0xffffu); acc[3] += bf2f(v.y >> 16);
        acc[4] += bf2f(v.z & 0xffffu); acc[5] += bf2f(v.z >> 16);
        acc[6] += bf2f(v.w & 0xffffu); acc[7] += bf2f(v.w >> 16);
    }
    float inv = (en > st) ? 1.0f / (float)(en - st) : 0.0f;
    uint4 o;
    o.x = (unsigned int)f2bf(acc[0] * inv) | ((unsigned int)f2bf(acc[1] * inv) << 16);
    o.y = (unsigned int)f2bf(acc[2] * inv) | ((unsigned int)f2bf(acc[3] * inv) << 16);
    o.z = (unsigned int)f2bf(acc[4] * inv) | ((unsigned int)f2bf(acc[5] * inv) << 16);
    o.w = (unsigned int)f2bf(acc[6] * inv) | ((unsigned int)f2bf(acc[7] * inv) << 16);
    *(uint4*)(meanb + (size_t)seg * DIM + lane * 8) = o;
}

// ===== 4-phase 256x256 GEMM — compiler-scheduled counted lgkmcnt (round-7) =====
// Same tiling/ledger/swizzle as round 6. Differences:
//  * PH_TOP/PH_BOT contain NO lgkmcnt(0) and NO sched_barrier(0): ds_reads are
//    compiler-visible loads, so the compiler emits stepped lgkmcnt(N) inside the
//    MFMA cluster (first MFMA needs only 5 of 12 reads) -> LDS drain overlaps MFMA.
//    Safety: every read is consumed by an MFMA before the bottom barrier, so all
//    reads are complete by bot-bar; stage(slot) still only overwrites retired slots.
//  * READ_B issued before READ_A8 (first MFMA consumes b0-3 + a0 = reads 1-5).

#define GLD16(g, l)                                                                     \
    __builtin_amdgcn_global_load_lds((const __attribute__((address_space(1))) void*)(g), \
                                     (__attribute__((address_space(3))) void*)(l), 16, 0, 0)

#define STAGE_A(tile, ksh, bufo) do {                                                   \
    int _pt = (tile) >> 3;                                                              \
    const unsigned short* _ab = (_pt == 0) ? xb : meanb + (size_t)(_pt - 1) * N_NODES * DIM; \
    int _kc = (((tile) & 7) << 6) + ((ksh) << 5) + gcol;  /* part-relative col */       \
    int _g0 = m0 + srow; if (_g0 >= N_NODES) _g0 = 0;                                   \
    int _g1 = m0 + srow + 128; if (_g1 >= N_NODES) _g1 = 0;                             \
    GLD16(_ab + (size_t)_g0 * DIM + _kc, S + (bufo) + ((ksh) * 8192) + (wid << 9));     \
    GLD16(_ab + (size_t)_g1 * DIM + _kc, S + (bufo) + ((ksh) * 8192) + 4096 + (wid << 9)); \
} while (0)

#define STAGE_B(tile, ksh, bufo) do {                                                   \
    int _kc = ((tile) << 6) + ((ksh) << 5) + gcol;        /* FULL k into wt */          \
    const unsigned short* _w0 = wt + (size_t)(n0 + srow) * KTOT + _kc;                  \
    GLD16(_w0, S + (bufo) + 16384 + ((ksh) * 8192) + (wid << 9));                       \
    GLD16(_w0 + (size_t)128 * KTOT, S + (bufo) + 16384 + ((ksh) * 8192) + 4096 + (wid << 9)); \
} while (0)

// arowF/brow0 are PRE-multiplied row bases (shorts). 16 rows = 512 shorts.
#define READ_A8(ks, bufo) do {                                                          \
    const unsigned short* _ap = S + (bufo) + (ks) * 8192 + arowF + cofs;                \
    a[0] = *(const short8*)(_ap);                                                       \
    a[1] = *(const short8*)(_ap + 512);                                                 \
    a[2] = *(const short8*)(_ap + 1024);                                                \
    a[3] = *(const short8*)(_ap + 1536);                                                \
    a[4] = *(const short8*)(_ap + 2048);                                                \
    a[5] = *(const short8*)(_ap + 2560);                                                \
    a[6] = *(const short8*)(_ap + 3072);                                                \
    a[7] = *(const short8*)(_ap + 3584);                                                \
} while (0)

#define READ_B(ks, bufo) do {                                                           \
    const unsigned short* _bp = S + (bufo) + 16384 + (ks) * 8192 + brow0 + cofs;        \
    b[0] = *(const short8*)(_bp);                                                       \
    b[1] = *(const short8*)(_bp + 512);                                                 \
    b[2] = *(const short8*)(_bp + 1024);                                                \
    b[3] = *(const short8*)(_bp + 1536);                                                \
} while (0)

#define MFMA32() do {                                                                   \
    _Pragma("unroll") for (int _m = 0; _m < 8; ++_m)                                    \
    _Pragma("unroll") for (int _n = 0; _n < 4; ++_n)                                    \
        acc[_m][_n] =                                                                   \
            __builtin_amdgcn_mfma_f32_16x16x32_bf16(a[_m], b[_n], acc[_m][_n], 0, 0, 0); \
} while (0)

#define PH_TOP()  __builtin_amdgcn_s_barrier(); __builtin_amdgcn_s_setprio(1)
#define PH_BOT()  __builtin_amdgcn_s_setprio(0); __builtin_amdgcn_s_barrier()
#define VMC4()    asm volatile("s_waitcnt vmcnt(4)" ::: "memory")
#define VMC0()    asm volatile("s_waitcnt vmcnt(0)" ::: "memory")
#define BUF1 32768

__global__ __launch_bounds__(512, 2) void k_gemm(const unsigned short* __restrict__ xb,
                                                 const unsigned short* __restrict__ meanb,
                                                 const unsigned short* __restrict__ wt,
                                                 const float* __restrict__ bias,
                                                 float* __restrict__ outf,
                                                 unsigned short* __restrict__ xbn,
                                                 int wf32, int wbf16) {
    extern __shared__ unsigned short S[];  // 131072 B
    int tid = threadIdx.x;
    int lane = tid & 63, wid = tid >> 6;

    // bijective XCD swizzle (m204): bn fastest so the 2 col-blocks of a row-panel
    // land on the same XCD's L2.
    int orig = blockIdx.x;
    int xcd = orig & 7, tix = orig >> 3;
    const int q = NWG_GEMM >> 3, r = NWG_GEMM & 7;  // 29, 4
    int wgid = (xcd < r ? xcd * (q + 1) : r * (q + 1) + (xcd - r) * q) + tix;
    int bn = wgid & 1, bm = wgid >> 1;
    int m0 = bm * 256, n0 = bn * 256;
    int wm = wid >> 2, wn = wid & 3;

    // ds_read-side constants; swizzle f depends only on r15 (invariant under +16k rows)
    int r15 = lane & 15, c4 = lane >> 4;
    int f = (r15 + (r15 >> 2)) & 3;
    int cofs = ((c4 ^ f) << 3);              // shorts
    int arowF = (wm * 128 + r15) * 32;       // row base, shorts
    int brow0 = (wn * 64 + r15) * 32;

    // stage-side constants (f_t invariant under +128 rows)
    int srow = tid >> 2;                     // 0..127
    int f_t = (srow + (srow >> 2)) & 3;
    int gcol = (((tid & 3) ^ f_t) << 3);     // pre-swizzled global source col (elements)

    short8 a[8], b[4];
    f32x4 acc[8][4] = {};

    // prologue: tile0 k0,k1 -> buf0; tile1 k0 -> buf1 (12 loads); VMC4 -> thru L8.
    STAGE_A(0, 0, 0);    STAGE_B(0, 0, 0);
    STAGE_A(0, 1, 0);    STAGE_B(0, 1, 0);
    STAGE_A(1, 0, BUF1); STAGE_B(1, 0, BUF1);
    VMC4();
    __builtin_amdgcn_s_barrier();

    for (int it = 0; it < NT / 2; ++it) {
        int t1 = 2 * it + 1, t2 = 2 * it + 2, t3 = 2 * it + 3;
        // ph1: read buf0 ks0 (tile 2it)     | stage B1-k1 (t1)
        READ_B(0, 0); READ_A8(0, 0);
        STAGE_A(t1, 1, BUF1); STAGE_B(t1, 1, BUF1);
        PH_TOP(); MFMA32(); PH_BOT();
        // ph2: read buf0 ks1                | stage b0-k0 (t2) | VMC4
        READ_B(1, 0); READ_A8(1, 0);
        if (t2 < NT) { STAGE_A(t2, 0, 0); STAGE_B(t2, 0, 0); VMC4(); } else { VMC0(); }
        PH_TOP(); MFMA32(); PH_BOT();
        // ph3: read buf1 ks0 (tile t1)      | stage b0-k1 (t2)
        READ_B(0, BUF1); READ_A8(0, BUF1);
        if (t2 < NT) { STAGE_A(t2, 1, 0); STAGE_B(t2, 1, 0); }
        PH_TOP(); MFMA32(); PH_BOT();
        // ph4: read buf1 ks1                | stage B1-k0 (t3) | VMC4
        READ_B(1, BUF1); READ_A8(1, BUF1);
        if (t3 < NT) { STAGE_A(t3, 0, BUF1); STAGE_B(t3, 0, BUF1); VMC4(); } else { VMC0(); }
        PH_TOP(); MFMA32(); PH_BOT();
    }
    VMC0();

    // epilogue: bias + relu + bf16 residual (xb is also A part 0 -> cache-hot)
    #pragma unroll
    for (int mm = 0; mm < 8; ++mm) {
        int rowoff = ((mm >> 2) << 6) + ((mm & 3) << 4);
        #pragma unroll
        for (int j = 0; j < 4; ++j) {
            int row = m0 + wm * 128 + rowoff + c4 * 4 + j;
            if (row >= N_NODES) continue;
            #pragma unroll
            for (int n = 0; n < 4; ++n) {
                int col = n0 + wn * 64 + n * 16 + r15;
                float v = acc[mm][n][j] + bias[col];
                v = fmaxf(v, 0.0f) + bf2f(xb[(size_t)row * DIM + col]);
                if (wf32)  outf[(size_t)row * DIM + col] = v;
                if (wbf16) xbn[(size_t)row * DIM + col] = f2bf(v);
            }
        }
    }
}

extern "C" void kernel_launch(void* const* d_in, const int* in_sizes, int n_in,
                              void* d_out, int out_size, void* d_ws, size_t ws_size,
                              hipStream_t stream) {
    const int* xidx   = (const int*)d_in[0];
    const int* eidx   = (const int*)d_in[1];
    const int* etype  = (const int*)d_in[2];
    const float* emb  = (const float*)d_in[3];
    const float* Wl[3]    = {(const float*)d_in[4], (const float*)d_in[7], (const float*)d_in[10]};
    const float* rootl[3] = {(const float*)d_in[5], (const float*)d_in[8], (const float*)d_in[11]};
    const float* bl[3]    = {(const float*)d_in[6], (const float*)d_in[9], (const float*)d_in[12]};
    const int* esrc = eidx;
    const int* edst = eidx + N_EDGES;

    char* ws = (char*)d_ws;
    size_t off = 0;
    auto take = [&](size_t bytes) { char* p = ws + off; off = (off + bytes + 255) & ~(size_t)255; return p; };
    unsigned short* xb0  = (unsigned short*)take((size_t)N_NODES * DIM * 2);
    unsigned short* xb1  = (unsigned short*)take((size_t)N_NODES * DIM * 2);
    unsigned short* meanb= (unsigned short*)take((size_t)NREL * N_NODES * DIM * 2);
    unsigned short* wcat = (unsigned short*)take((size_t)3 * DIM * KTOT * 2);
    int* hist    = (int*)take((size_t)NSEG * 4);
    int* offsets = (int*)take((size_t)(NSEG + 1) * 4);
    int* cursor  = (int*)take((size_t)NSEG * 4);
    int* bsums   = (int*)take(64 * 4);
    int* ssrc    = (int*)take((size_t)N_EDGES * 4);

    hipMemsetAsync(hist, 0, (size_t)NSEG * 4, stream);
    hipMemsetAsync(cursor, 0, (size_t)NSEG * 4, stream);
    dim3 wg((DIM * KTOT + 255) / 256, 3);
    k_wcat3<<<wg, 256, 0, stream>>>(Wl[0], rootl[0], Wl[1], rootl[1], Wl[2], rootl[2], wcat);
    k_embed<<<N_NODES, 64, 0, stream>>>(xidx, emb, xb0);
    k_hist<<<(N_EDGES + 255) / 256, 256, 0, stream>>>(etype, edst, hist);
    k_scan1<<<(NSEG + 2047) / 2048, 256, 0, stream>>>(hist, offsets, bsums);
    k_scan2<<<1, 64, 0, stream>>>(bsums, (NSEG + 2047) / 2048);
    k_scan3<<<(NSEG + 2047) / 2048, 256, 0, stream>>>(bsums, offsets);
    k_scatter<<<(N_EDGES + 255) / 256, 256, 0, stream>>>(etype, esrc, edst, offsets, cursor, ssrc);

    unsigned short* xb_cur = xb0;
    unsigned short* xb_nxt = xb1;
    for (int l = 0; l < 3; l++) {
        k_agg<<<N_NODES, 256, 0, stream>>>(xb_cur, ssrc, offsets, meanb);
        int last = (l == 2);
        k_gemm<<<NWG_GEMM, 512, 131072, stream>>>(xb_cur, meanb, wcat + (size_t)l * DIM * KTOT,
                                                  bl[l], (float*)d_out, xb_nxt,
                                                  last ? 1 : 0, last ? 0 : 1);
        unsigned short* t = xb_cur; xb_cur = xb_nxt; xb_nxt = t;
    }
}

// Round 8
// 754.392 us; speedup vs baseline: 1.0143x; 1.0143x over previous
//
#include <hip/hip_runtime.h>
#include <hip/hip_bf16.h>

#define N_NODES 30000
#define N_EDGES 480000
#define DIM 512
#define NREL 4
#define NSEG (NREL * N_NODES)   // 120000
#define KTOT ((NREL + 1) * DIM) // 2560
#define NT (KTOT / 64)          // 40 K-tiles of 64
#define NBM ((N_NODES + 255) / 256)  // 118
#define NWG_GEMM (NBM * 2)           // 236

typedef __attribute__((ext_vector_type(8))) short short8;
typedef __attribute__((ext_vector_type(4))) float f32x4;

__device__ __forceinline__ float bf2f(unsigned int hi) {
    union { unsigned int u; float f; } v; v.u = hi << 16; return v.f;
}
__device__ __forceinline__ unsigned short f2bf(float f) {
    union { float f; unsigned int u; } v; v.f = f;
    unsigned int u = v.u;
    unsigned int r = (u + 0x7fffu + ((u >> 16) & 1u)) >> 16;
    return (unsigned short)r;
}

// ---------------- prep: WcatT build (B^T layout: [e][k], k<512 -> root, else W[r]) -----
__global__ void k_wcat(const float* __restrict__ W, const float* __restrict__ root,
                       unsigned short* __restrict__ wt) {
    int i = blockIdx.x * 256 + threadIdx.x;       // over 512*2560, k fastest
    if (i >= DIM * KTOT) return;
    int k = i % KTOT, e = i / KTOT;
    float v;
    if (k < DIM) {
        v = root[k * DIM + e];
    } else {
        int kk = k - DIM;
        int r = kk >> 9; kk &= 511;
        v = W[(size_t)r * DIM * DIM + (size_t)kk * DIM + e];
    }
    wt[(size_t)e * KTOT + k] = f2bf(v);
}

// ---------------- prep: x0 = emb[x_idx] (bf16 only) ----------------
__global__ void k_embed(const int* __restrict__ xidx, const float* __restrict__ emb,
                        unsigned short* __restrict__ xb) {
    int n = blockIdx.x;           // 30000
    int l = threadIdx.x;          // 64
    int id = xidx[n];
    const float4* er = (const float4*)(emb + (size_t)id * DIM + l * 8);
    float4 a = er[0], b = er[1];
    ushort4 pa, pb;
    pa.x = f2bf(a.x); pa.y = f2bf(a.y); pa.z = f2bf(a.z); pa.w = f2bf(a.w);
    pb.x = f2bf(b.x); pb.y = f2bf(b.y); pb.z = f2bf(b.z); pb.w = f2bf(b.w);
    ushort4* xbo = (ushort4*)(xb + (size_t)n * DIM + l * 8);
    xbo[0] = pa; xbo[1] = pb;
}

// ---------------- counting sort of edges by seg = etype*N + dst ----------------
__global__ void k_hist(const int* __restrict__ etype, const int* __restrict__ dst,
                       int* __restrict__ hist) {
    int e = blockIdx.x * 256 + threadIdx.x;
    if (e < N_EDGES) atomicAdd(&hist[etype[e] * N_NODES + dst[e]], 1);
}

__global__ void k_scan1(const int* __restrict__ hist, int* __restrict__ offsets,
                        int* __restrict__ bsums) {
    __shared__ int sdata[256];
    int t = threadIdx.x, b = blockIdx.x;
    int base = b * 2048 + t * 8;
    int v[8]; int s = 0;
    #pragma unroll
    for (int i = 0; i < 8; i++) {
        int idx = base + i;
        v[i] = (idx < NSEG) ? hist[idx] : 0;
        s += v[i];
    }
    sdata[t] = s; __syncthreads();
    for (int off = 1; off < 256; off <<= 1) {
        int x = (t >= off) ? sdata[t - off] : 0;
        __syncthreads();
        sdata[t] += x;
        __syncthreads();
    }
    int run = (t == 0) ? 0 : sdata[t - 1];
    #pragma unroll
    for (int i = 0; i < 8; i++) {
        run += v[i];
        int idx = base + i;
        if (idx < NSEG) offsets[idx + 1] = run;
    }
    if (t == 255) bsums[b] = sdata[255];
}

__global__ void k_scan2(int* __restrict__ bsums, int nb) {
    if (threadIdx.x == 0 && blockIdx.x == 0) {
        int run = 0;
        for (int i = 0; i < nb; i++) { int v = bsums[i]; bsums[i] = run; run += v; }
    }
}

__global__ void k_scan3(const int* __restrict__ bsums, int* __restrict__ offsets) {
    int t = threadIdx.x, b = blockIdx.x;
    int base = b * 2048 + t * 8;
    int add = bsums[b];
    #pragma unroll
    for (int i = 0; i < 8; i++) {
        int idx = base + i;
        if (idx < NSEG) offsets[idx + 1] += add;
    }
    if (b == 0 && t == 0) offsets[0] = 0;
}

__global__ void k_scatter(const int* __restrict__ etype, const int* __restrict__ src,
                          const int* __restrict__ dst, const int* __restrict__ offsets,
                          int* __restrict__ cursor, int* __restrict__ ssrc) {
    int e = blockIdx.x * 256 + threadIdx.x;
    if (e < N_EDGES) {
        int seg = etype[e] * N_NODES + dst[e];
        int p = atomicAdd(&cursor[seg], 1);
        ssrc[offsets[seg] + p] = src[e];
    }
}

// ---------------- per-layer segment-mean (reads bf16 x, writes bf16 mean) ----------------
__global__ __launch_bounds__(256) void k_agg(const unsigned short* __restrict__ xb,
                                             const int* __restrict__ ssrc,
                                             const int* __restrict__ offsets,
                                             unsigned short* __restrict__ meanb) {
    int wid = threadIdx.x >> 6, lane = threadIdx.x & 63;
    int seg = blockIdx.x * 4 + wid;
    int st = offsets[seg], en = offsets[seg + 1];
    float acc[8] = {0, 0, 0, 0, 0, 0, 0, 0};
    int i = st;
    for (; i + 1 < en; i += 2) {
        int s0 = ssrc[i], s1 = ssrc[i + 1];
        uint4 v0 = *(const uint4*)(xb + (size_t)s0 * DIM + lane * 8);
        uint4 v1 = *(const uint4*)(xb + (size_t)s1 * DIM + lane * 8);
        acc[0] += bf2f(v0.x & 0xffffu) + bf2f(v1.x & 0xffffu);
        acc[1] += bf2f(v0.x >> 16)     + bf2f(v1.x >> 16);
        acc[2] += bf2f(v0.y & 0xffffu) + bf2f(v1.y & 0xffffu);
        acc[3] += bf2f(v0.y >> 16)     + bf2f(v1.y >> 16);
        acc[4] += bf2f(v0.z & 0xffffu) + bf2f(v1.z & 0xffffu);
        acc[5] += bf2f(v0.z >> 16)     + bf2f(v1.z >> 16);
        acc[6] += bf2f(v0.w & 0xffffu) + bf2f(v1.w & 0xffffu);
        acc[7] += bf2f(v0.w >> 16)     + bf2f(v1.w >> 16);
    }
    if (i < en) {
        int s = ssrc[i];
        uint4 v = *(const uint4*)(xb + (size_t)s * DIM + lane * 8);
        acc[0] += bf2f(v.x & 0xffffu); acc[1] += bf2f(v.x >> 16);
        acc[2] += bf2f(v.y & 0xffffu); acc[3] += bf2f(v.y >> 16);
        acc[4] += bf2f(v.z & 0xffffu); acc[5] += bf2f(v.z >> 16);
        acc[6] += bf2f(v.w & 0xffffu); acc[7] += bf2f(v.w >> 16);
    }
    float inv = (en > st) ? 1.0f / (float)(en - st) : 0.0f;
    uint4 o;
    o.x = (unsigned int)f2bf(acc[0] * inv) | ((unsigned int)f2bf(acc[1] * inv) << 16);
    o.y = (unsigned int)f2bf(acc[2] * inv) | ((unsigned int)f2bf(acc[3] * inv) << 16);
    o.z = (unsigned int)f2bf(acc[4] * inv) | ((unsigned int)f2bf(acc[5] * inv) << 16);
    o.w = (unsigned int)f2bf(acc[6] * inv) | ((unsigned int)f2bf(acc[7] * inv) << 16);
    *(uint4*)(meanb + (size_t)seg * DIM + lane * 8) = o;
}

// ===== 8-phase 256x256 GEMM with REGISTER READ-AHEAD (round-8) =====
// Base = round-5 schedule (115.5us). Change: phase k issues ds_reads for phase
// k+1 into alternating register sets (a0/a1 per phase, rb0/rb1 per 2 phases);
// MFMA(k) consumes regs loaded at k-1. No lgkmcnt(0) in the loop: the compiler
// emits a COUNTED lgkmcnt (= the just-issued reads) before the MFMA cluster,
// so the LDS drain overlaps the MFMA burst.
// Ledger (hand-verified, loads L1..L16/iter identical to R5):
//  - stage-after-last-read gap = exactly 2 phases for every slot (reads complete
//    before their consuming MFMA -> before bar2 -> before the stage's issue).
//  - RAW checkpoints: VMC4 at ph3 (covers thru L2: prevL11-16 + L1,2 for reads
//    ph4-ph7) and VMC4 at ph7 (covers thru L10: L3-L10 for reads ph8-ph3').
//    Prologue: VMC6 (covers loads 1-8 for reads ph0-ph3). Tail: VMC0.
//  - ph8's read (next-iter tile) guarded by t2<NT.

#define GLD16(g, l)                                                                     \
    __builtin_amdgcn_global_load_lds((const __attribute__((address_space(1))) void*)(g), \
                                     (__attribute__((address_space(3))) void*)(l), 16, 0, 0)

#define STAGE_A(tile, ksh, bufo) do {                                                   \
    int _pt = (tile) >> 3;                                                              \
    const unsigned short* _ab = (_pt == 0) ? xb : meanb + (size_t)(_pt - 1) * N_NODES * DIM; \
    int _kc = (((tile) & 7) << 6) + ((ksh) << 5) + gcol;  /* part-relative col */       \
    int _g0 = m0 + srow; if (_g0 >= N_NODES) _g0 = 0;                                   \
    int _g1 = m0 + srow + 128; if (_g1 >= N_NODES) _g1 = 0;                             \
    GLD16(_ab + (size_t)_g0 * DIM + _kc, S + (bufo) + ((ksh) * 8192) + (wid << 9));     \
    GLD16(_ab + (size_t)_g1 * DIM + _kc, S + (bufo) + ((ksh) * 8192) + 4096 + (wid << 9)); \
} while (0)

#define STAGE_B(tile, ksh, bufo) do {                                                   \
    int _kc = ((tile) << 6) + ((ksh) << 5) + gcol;        /* FULL k into wt */          \
    const unsigned short* _w0 = wt + (size_t)(n0 + srow) * KTOT + _kc;                  \
    GLD16(_w0, S + (bufo) + 16384 + ((ksh) * 8192) + (wid << 9));                       \
    GLD16(_w0 + (size_t)128 * KTOT, S + (bufo) + 16384 + ((ksh) * 8192) + 4096 + (wid << 9)); \
} while (0)

// arowF/brow0 are PRE-multiplied row bases (shorts). mq offset = 64 rows = 2048 shorts.
#define RD_A(dst, ks, mq, bufo) do {                                                    \
    const unsigned short* _ap = S + (bufo) + (ks) * 8192 + arowF + (mq) * 2048 + cofs;  \
    dst[0] = *(const short8*)(_ap);                                                     \
    dst[1] = *(const short8*)(_ap + 512);                                               \
    dst[2] = *(const short8*)(_ap + 1024);                                              \
    dst[3] = *(const short8*)(_ap + 1536);                                              \
} while (0)

#define RD_B(dst, ks, bufo) do {                                                        \
    const unsigned short* _bp = S + (bufo) + 16384 + (ks) * 8192 + brow0 + cofs;        \
    dst[0] = *(const short8*)(_bp);                                                     \
    dst[1] = *(const short8*)(_bp + 512);                                               \
    dst[2] = *(const short8*)(_bp + 1024);                                              \
    dst[3] = *(const short8*)(_bp + 1536);                                              \
} while (0)

#define MFMAH(av, bv, h) do {                                                           \
    _Pragma("unroll") for (int _m = 0; _m < 4; ++_m)                                    \
    _Pragma("unroll") for (int _n = 0; _n < 4; ++_n)                                    \
        acc[(h) * 4 + _m][_n] =                                                         \
            __builtin_amdgcn_mfma_f32_16x16x32_bf16(av[_m], bv[_n], acc[(h) * 4 + _m][_n], 0, 0, 0); \
} while (0)

#define PH_TOP()  __builtin_amdgcn_s_barrier(); __builtin_amdgcn_sched_barrier(0);      \
                  __builtin_amdgcn_s_setprio(1)
#define PH_BOT()  __builtin_amdgcn_s_setprio(0); __builtin_amdgcn_sched_barrier(0);     \
                  __builtin_amdgcn_s_barrier()
#define VMC6()    asm volatile("s_waitcnt vmcnt(6)" ::: "memory")
#define VMC4()    asm volatile("s_waitcnt vmcnt(4)" ::: "memory")
#define VMC0()    asm volatile("s_waitcnt vmcnt(0)" ::: "memory")
#define BUF1 32768

__global__ __launch_bounds__(512, 2) void k_gemm(const unsigned short* __restrict__ xb,
                                                 const unsigned short* __restrict__ meanb,
                                                 const unsigned short* __restrict__ wt,
                                                 const float* __restrict__ bias,
                                                 float* __restrict__ outf,
                                                 unsigned short* __restrict__ xbn,
                                                 int wf32, int wbf16) {
    extern __shared__ unsigned short S[];  // 131072 B
    int tid = threadIdx.x;
    int lane = tid & 63, wid = tid >> 6;

    // bijective XCD swizzle (m204)
    int orig = blockIdx.x;
    int xcd = orig & 7, tix = orig >> 3;
    const int q = NWG_GEMM >> 3, r = NWG_GEMM & 7;  // 29, 4
    int wgid = (xcd < r ? xcd * (q + 1) : r * (q + 1) + (xcd - r) * q) + tix;
    int bn = wgid & 1, bm = wgid >> 1;
    int m0 = bm * 256, n0 = bn * 256;
    int wm = wid >> 2, wn = wid & 3;

    // ds_read-side constants; swizzle f depends only on r15
    int r15 = lane & 15, c4 = lane >> 4;
    int f = (r15 + (r15 >> 2)) & 3;
    int cofs = ((c4 ^ f) << 3);              // shorts
    int arowF = (wm * 128 + r15) * 32;       // row base, shorts
    int brow0 = (wn * 64 + r15) * 32;

    // stage-side constants
    int srow = tid >> 2;                     // 0..127
    int f_t = (srow + (srow >> 2)) & 3;
    int gcol = (((tid & 3) ^ f_t) << 3);     // pre-swizzled global source col (elements)

    short8 a0[4], a1[4], rb0[4], rb1[4];
    f32x4 acc[8][4] = {};

    // prologue: tile0 (4 slots)->buf0, tile1 (3 slots)->buf1: loads [1..14].
    // VMC6 -> thru [8] = B00,A00,B01,A01 (covers prologue-read + ph1-ph3 reads).
    STAGE_B(0, 0, 0); STAGE_A(0, 0, 0); STAGE_B(0, 1, 0); STAGE_A(0, 1, 0);
    STAGE_B(1, 0, BUF1); STAGE_A(1, 0, BUF1); STAGE_B(1, 1, BUF1);
    VMC6();
    __builtin_amdgcn_s_barrier();
    __builtin_amdgcn_sched_barrier(0);
    RD_A(a0, 0, 0, 0); RD_B(rb0, 0, 0);      // regs for ph1

    for (int it = 0; it < NT / 2; ++it) {
        int t1 = 2 * it + 1, t2 = 2 * it + 2, t3 = 2 * it + 3;
        // ph1: MFMA(a0,rb0)->L | Rd a1<-A(k0,mq1,b0) | St A(t1,k1,b1) [L1,2]
        RD_A(a1, 0, 1, 0);
        STAGE_A(t1, 1, BUF1);
        PH_TOP(); MFMAH(a0, rb0, 0); PH_BOT();
        // ph2: MFMA(a1,rb0)->H | Rd a0<-A(k1,mq0,b0), rb1<-B(k1,b0) | St B(t2,k0,b0) [L3,4]
        RD_A(a0, 1, 0, 0); RD_B(rb1, 1, 0);
        if (t2 < NT) STAGE_B(t2, 0, 0);
        PH_TOP(); MFMAH(a1, rb0, 1); PH_BOT();
        // ph3: MFMA(a0,rb1)->L | Rd a1<-A(k1,mq1,b0) | St A(t2,k0,b0) [L5,6] | VMC4
        RD_A(a1, 1, 1, 0);
        if (t2 < NT) { STAGE_A(t2, 0, 0); VMC4(); } else { VMC0(); }
        PH_TOP(); MFMAH(a0, rb1, 0); PH_BOT();
        // ph4: MFMA(a1,rb1)->H | Rd a0<-A(k0,mq0,b1), rb0<-B(k0,b1) | St B(t2,k1,b0) [L7,8]
        RD_A(a0, 0, 0, BUF1); RD_B(rb0, 0, BUF1);
        if (t2 < NT) STAGE_B(t2, 1, 0);
        PH_TOP(); MFMAH(a1, rb1, 1); PH_BOT();
        // ph5: MFMA(a0,rb0)->L | Rd a1<-A(k0,mq1,b1) | St A(t2,k1,b0) [L9,10]
        RD_A(a1, 0, 1, BUF1);
        if (t2 < NT) STAGE_A(t2, 1, 0);
        PH_TOP(); MFMAH(a0, rb0, 0); PH_BOT();
        // ph6: MFMA(a1,rb0)->H | Rd a0<-A(k1,mq0,b1), rb1<-B(k1,b1) | St B(t3,k0,b1) [L11,12]
        RD_A(a0, 1, 0, BUF1); RD_B(rb1, 1, BUF1);
        if (t3 < NT) STAGE_B(t3, 0, BUF1);
        PH_TOP(); MFMAH(a1, rb0, 1); PH_BOT();
        // ph7: MFMA(a0,rb1)->L | Rd a1<-A(k1,mq1,b1) | St A(t3,k0,b1) [L13,14] | VMC4
        RD_A(a1, 1, 1, BUF1);
        if (t3 < NT) { STAGE_A(t3, 0, BUF1); VMC4(); } else { VMC0(); }
        PH_TOP(); MFMAH(a0, rb1, 0); PH_BOT();
        // ph8: MFMA(a1,rb1)->H | Rd a0<-A(k0,mq0,b0:t2), rb0<-B(k0,b0:t2) | St B(t3,k1,b1) [L15,16]
        if (t2 < NT) { RD_A(a0, 0, 0, 0); RD_B(rb0, 0, 0); }
        if (t3 < NT) STAGE_B(t3, 1, BUF1);
        PH_TOP(); MFMAH(a1, rb1, 1); PH_BOT();
    }
    VMC0();

    // epilogue: bias + relu + bf16 residual (xb is also A part 0 -> cache-hot)
    #pragma unroll
    for (int mm = 0; mm < 8; ++mm) {
        int rowoff = ((mm >> 2) << 6) + ((mm & 3) << 4);
        #pragma unroll
        for (int j = 0; j < 4; ++j) {
            int row = m0 + wm * 128 + rowoff + c4 * 4 + j;
            if (row >= N_NODES) continue;
            #pragma unroll
            for (int n = 0; n < 4; ++n) {
                int col = n0 + wn * 64 + n * 16 + r15;
                float v = acc[mm][n][j] + bias[col];
                v = fmaxf(v, 0.0f) + bf2f(xb[(size_t)row * DIM + col]);
                if (wf32)  outf[(size_t)row * DIM + col] = v;
                if (wbf16) xbn[(size_t)row * DIM + col] = f2bf(v);
            }
        }
    }
}

extern "C" void kernel_launch(void* const* d_in, const int* in_sizes, int n_in,
                              void* d_out, int out_size, void* d_ws, size_t ws_size,
                              hipStream_t stream) {
    const int* xidx   = (const int*)d_in[0];
    const int* eidx   = (const int*)d_in[1];
    const int* etype  = (const int*)d_in[2];
    const float* emb  = (const float*)d_in[3];
    const float* Wl[3]    = {(const float*)d_in[4], (const float*)d_in[7], (const float*)d_in[10]};
    const float* rootl[3] = {(const float*)d_in[5], (const float*)d_in[8], (const float*)d_in[11]};
    const float* bl[3]    = {(const float*)d_in[6], (const float*)d_in[9], (const float*)d_in[12]};
    const int* esrc = eidx;
    const int* edst = eidx + N_EDGES;

    char* ws = (char*)d_ws;
    size_t off = 0;
    auto take = [&](size_t bytes) { char* p = ws + off; off = (off + bytes + 255) & ~(size_t)255; return p; };
    unsigned short* xb0  = (unsigned short*)take((size_t)N_NODES * DIM * 2);
    unsigned short* xb1  = (unsigned short*)take((size_t)N_NODES * DIM * 2);
    unsigned short* meanb= (unsigned short*)take((size_t)NREL * N_NODES * DIM * 2);
    unsigned short* wcat = (unsigned short*)take((size_t)3 * DIM * KTOT * 2);
    int* hist    = (int*)take((size_t)NSEG * 4);
    int* offsets = (int*)take((size_t)(NSEG + 1) * 4);
    int* cursor  = (int*)take((size_t)NSEG * 4);
    int* bsums   = (int*)take(64 * 4);
    int* ssrc    = (int*)take((size_t)N_EDGES * 4);

    hipMemsetAsync(hist, 0, (size_t)NSEG * 4, stream);
    hipMemsetAsync(cursor, 0, (size_t)NSEG * 4, stream);
    for (int l = 0; l < 3; l++) {
        k_wcat<<<(DIM * KTOT + 255) / 256, 256, 0, stream>>>(Wl[l], rootl[l],
                                                             wcat + (size_t)l * DIM * KTOT);
    }
    k_embed<<<N_NODES, 64, 0, stream>>>(xidx, emb, xb0);
    k_hist<<<(N_EDGES + 255) / 256, 256, 0, stream>>>(etype, edst, hist);
    k_scan1<<<(NSEG + 2047) / 2048, 256, 0, stream>>>(hist, offsets, bsums);
    k_scan2<<<1, 64, 0, stream>>>(bsums, (NSEG + 2047) / 2048);
    k_scan3<<<(NSEG + 2047) / 2048, 256, 0, stream>>>(bsums, offsets);
    k_scatter<<<(N_EDGES + 255) / 256, 256, 0, stream>>>(etype, esrc, edst, offsets, cursor, ssrc);

    unsigned short* xb_cur = xb0;
    unsigned short* xb_nxt = xb1;
    for (int l = 0; l < 3; l++) {
        k_agg<<<N_NODES, 256, 0, stream>>>(xb_cur, ssrc, offsets, meanb);
        int last = (l == 2);
        k_gemm<<<NWG_GEMM, 512, 131072, stream>>>(xb_cur, meanb, wcat + (size_t)l * DIM * KTOT,
                                                  bl[l], (float*)d_out, xb_nxt,
                                                  last ? 1 : 0, last ? 0 : 1);
        unsigned short* t = xb_cur; xb_cur = xb_nxt; xb_nxt = t;
    }
}

// Round 9
// 620.245 us; speedup vs baseline: 1.2336x; 1.2163x over previous
//
#include <hip/hip_runtime.h>
#include <hip/hip_bf16.h>

#define N_NODES 30000
#define N_EDGES 480000
#define DIM 512
#define NREL 4
#define NSEG (NREL * N_NODES)   // 120000
#define KTOT ((NREL + 1) * DIM) // 2560
#define NT (KTOT / 64)          // 40 K-tiles of 64
#define NBM ((N_NODES + 255) / 256)  // 118
#define NWG_GEMM (NBM * 2)           // 236

typedef __attribute__((ext_vector_type(8))) short short8;
typedef __attribute__((ext_vector_type(4))) float f32x4;

__device__ __forceinline__ float bf2f(unsigned int hi) {
    union { unsigned int u; float f; } v; v.u = hi << 16; return v.f;
}
__device__ __forceinline__ unsigned short f2bf(float f) {
    union { float f; unsigned int u; } v; v.f = f;
    unsigned int u = v.u;
    unsigned int r = (u + 0x7fffu + ((u >> 16) & 1u)) >> 16;
    return (unsigned short)r;
}

// ---------------- prep: WcatT build (B^T layout: [e][k], k<512 -> root, else W[r]) -----
__global__ void k_wcat(const float* __restrict__ W, const float* __restrict__ root,
                       unsigned short* __restrict__ wt) {
    int i = blockIdx.x * 256 + threadIdx.x;       // over 512*2560, k fastest
    if (i >= DIM * KTOT) return;
    int k = i % KTOT, e = i / KTOT;
    float v;
    if (k < DIM) {
        v = root[k * DIM + e];
    } else {
        int kk = k - DIM;
        int r = kk >> 9; kk &= 511;
        v = W[(size_t)r * DIM * DIM + (size_t)kk * DIM + e];
    }
    wt[(size_t)e * KTOT + k] = f2bf(v);
}

// ---------------- prep: x0 = emb[x_idx] (bf16 only); 4 nodes per 256-thread block ----
__global__ void k_embed(const int* __restrict__ xidx, const float* __restrict__ emb,
                        unsigned short* __restrict__ xb) {
    int n = blockIdx.x * 4 + (threadIdx.x >> 6);   // 7500 blocks
    int l = threadIdx.x & 63;
    if (n >= N_NODES) return;
    int id = xidx[n];
    const float4* er = (const float4*)(emb + (size_t)id * DIM + l * 8);
    float4 a = er[0], b = er[1];
    ushort4 pa, pb;
    pa.x = f2bf(a.x); pa.y = f2bf(a.y); pa.z = f2bf(a.z); pa.w = f2bf(a.w);
    pb.x = f2bf(b.x); pb.y = f2bf(b.y); pb.z = f2bf(b.z); pb.w = f2bf(b.w);
    ushort4* xbo = (ushort4*)(xb + (size_t)n * DIM + l * 8);
    xbo[0] = pa; xbo[1] = pb;
}

// ---------------- counting sort of edges by seg = etype*N + dst ----------------
__global__ void k_hist(const int* __restrict__ etype, const int* __restrict__ dst,
                       int* __restrict__ hist) {
    int e = blockIdx.x * 256 + threadIdx.x;
    if (e < N_EDGES) atomicAdd(&hist[etype[e] * N_NODES + dst[e]], 1);
}

__global__ void k_scan1(const int* __restrict__ hist, int* __restrict__ offsets,
                        int* __restrict__ bsums) {
    __shared__ int sdata[256];
    int t = threadIdx.x, b = blockIdx.x;
    int base = b * 2048 + t * 8;
    int v[8]; int s = 0;
    #pragma unroll
    for (int i = 0; i < 8; i++) {
        int idx = base + i;
        v[i] = (idx < NSEG) ? hist[idx] : 0;
        s += v[i];
    }
    sdata[t] = s; __syncthreads();
    for (int off = 1; off < 256; off <<= 1) {
        int x = (t >= off) ? sdata[t - off] : 0;
        __syncthreads();
        sdata[t] += x;
        __syncthreads();
    }
    int run = (t == 0) ? 0 : sdata[t - 1];
    #pragma unroll
    for (int i = 0; i < 8; i++) {
        run += v[i];
        int idx = base + i;
        if (idx < NSEG) offsets[idx + 1] = run;
    }
    if (t == 255) bsums[b] = sdata[255];
}

__global__ void k_scan2(int* __restrict__ bsums, int nb) {
    if (threadIdx.x == 0 && blockIdx.x == 0) {
        int run = 0;
        for (int i = 0; i < nb; i++) { int v = bsums[i]; bsums[i] = run; run += v; }
    }
}

__global__ void k_scan3(const int* __restrict__ bsums, int* __restrict__ offsets) {
    int t = threadIdx.x, b = blockIdx.x;
    int base = b * 2048 + t * 8;
    int add = bsums[b];
    #pragma unroll
    for (int i = 0; i < 8; i++) {
        int idx = base + i;
        if (idx < NSEG) offsets[idx + 1] += add;
    }
    if (b == 0 && t == 0) offsets[0] = 0;
}

__global__ void k_scatter(const int* __restrict__ etype, const int* __restrict__ src,
                          const int* __restrict__ dst, const int* __restrict__ offsets,
                          int* __restrict__ cursor, int* __restrict__ ssrc) {
    int e = blockIdx.x * 256 + threadIdx.x;
    if (e < N_EDGES) {
        int seg = etype[e] * N_NODES + dst[e];
        int p = atomicAdd(&cursor[seg], 1);
        ssrc[offsets[seg] + p] = src[e];
    }
}

// ---------------- per-layer segment-mean (reads bf16 x, writes bf16 mean) ----------------
__global__ __launch_bounds__(256) void k_agg(const unsigned short* __restrict__ xb,
                                             const int* __restrict__ ssrc,
                                             const int* __restrict__ offsets,
                                             unsigned short* __restrict__ meanb) {
    int wid = threadIdx.x >> 6, lane = threadIdx.x & 63;
    int seg = blockIdx.x * 4 + wid;
    int st = offsets[seg], en = offsets[seg + 1];
    float acc[8] = {0, 0, 0, 0, 0, 0, 0, 0};
    int i = st;
    for (; i + 1 < en; i += 2) {
        int s0 = ssrc[i], s1 = ssrc[i + 1];
        uint4 v0 = *(const uint4*)(xb + (size_t)s0 * DIM + lane * 8);
        uint4 v1 = *(const uint4*)(xb + (size_t)s1 * DIM + lane * 8);
        acc[0] += bf2f(v0.x & 0xffffu) + bf2f(v1.x & 0xffffu);
        acc[1] += bf2f(v0.x >> 16)     + bf2f(v1.x >> 16);
        acc[2] += bf2f(v0.y & 0xffffu) + bf2f(v1.y & 0xffffu);
        acc[3] += bf2f(v0.y >> 16)     + bf2f(v1.y >> 16);
        acc[4] += bf2f(v0.z & 0xffffu) + bf2f(v1.z & 0xffffu);
        acc[5] += bf2f(v0.z >> 16)     + bf2f(v1.z >> 16);
        acc[6] += bf2f(v0.w & 0xffffu) + bf2f(v1.w & 0xffffu);
        acc[7] += bf2f(v0.w >> 16)     + bf2f(v1.w >> 16);
    }
    if (i < en) {
        int s = ssrc[i];
        uint4 v = *(const uint4*)(xb + (size_t)s * DIM + lane * 8);
        acc[0] += bf2f(v.x & 0xffffu); acc[1] += bf2f(v.x >> 16);
        acc[2] += bf2f(v.y & 0xffffu); acc[3] += bf2f(v.y >> 16);
        acc[4] += bf2f(v.z & 0xffffu); acc[5] += bf2f(v.z >> 16);
        acc[6] += bf2f(v.w & 0xffffu); acc[7] += bf2f(v.w >> 16);
    }
    float inv = (en > st) ? 1.0f / (float)(en - st) : 0.0f;
    uint4 o;
    o.x = (unsigned int)f2bf(acc[0] * inv) | ((unsigned int)f2bf(acc[1] * inv) << 16);
    o.y = (unsigned int)f2bf(acc[2] * inv) | ((unsigned int)f2bf(acc[3] * inv) << 16);
    o.z = (unsigned int)f2bf(acc[4] * inv) | ((unsigned int)f2bf(acc[5] * inv) << 16);
    o.w = (unsigned int)f2bf(acc[6] * inv) | ((unsigned int)f2bf(acc[7] * inv) << 16);
    *(uint4*)(meanb + (size_t)seg * DIM + lane * 8) = o;
}

// ===== 8-phase 256x256 GEMM — gap-2 slot schedule, SINGLE barrier/phase (round-9) ====
// Reads identical to R5. Stages shifted so every slot's restage is >=2 regions after
// its last read:  ph1: B(t1,k1,b1)          ph2: -            (VMC6)
//                 ph3: A(t1,k1,b1)+B(t2,k0,b0)   ph4: A(t2,k0,b0)  (VMC6)
//                 ph5: B(t2,k1,b0)          ph6: A(t2,k1,b0)  (VMC6)
//                 ph7: B(t3,k0,b1)          ph8: A(t3,k0,b1)  (VMC6)
// With gap>=2, the bottom barrier is provably redundant for the WAR hazard (a wave's
// reads of region p drain at its own lgkmcnt(0) right after TOP(p); any stage of that
// slot issues after TOP(p+1), which all waves reach only after that drain), so each
// phase has ONE s_barrier -> fast waves run ahead into the next read region while slow
// waves finish MFMA: the LDS pipe stays fed during MFMA regions.
// RAW ledger (hand-verified, 16 loads/iter): VMC6@ph2 -> complete thru ph6(i-1)
// (covers ph3/ph4 reads of A-k1-b0@ph6(i-1) and ph3's B-k1-b0@ph5(i-1));
// VMC6@ph4 -> thru ph1(i) (covers ph5 reads staged ph7/ph8(i-1)); VMC6@ph6 -> thru
// ph3(i) (covers ph7/ph8 reads of A-k1-b1@ph3(i), B-k1-b1@ph1(i)); VMC6@ph8 -> thru
// ph5(i) (covers ph1(i+1) reads staged ph3/ph4(i)). Prologue 12 loads + VMC4 (tile0
// landed). Final iter (t2/t3>=NT): skipped stages -> degrade ph4/ph6/ph8 to VMC0.
// Same-region read/stage slot sets verified disjoint for all 8 phases.

#define GLD16(g, l)                                                                     \
    __builtin_amdgcn_global_load_lds((const __attribute__((address_space(1))) void*)(g), \
                                     (__attribute__((address_space(3))) void*)(l), 16, 0, 0)

#define STAGE_A(tile, ksh, bufo) do {                                                   \
    int _pt = (tile) >> 3;                                                              \
    const unsigned short* _ab = (_pt == 0) ? xb : meanb + (size_t)(_pt - 1) * N_NODES * DIM; \
    int _kc = (((tile) & 7) << 6) + ((ksh) << 5) + gcol;  /* part-relative col */       \
    int _g0 = m0 + srow; if (_g0 >= N_NODES) _g0 = 0;                                   \
    int _g1 = m0 + srow + 128; if (_g1 >= N_NODES) _g1 = 0;                             \
    GLD16(_ab + (size_t)_g0 * DIM + _kc, S + (bufo) + ((ksh) * 8192) + (wid << 9));     \
    GLD16(_ab + (size_t)_g1 * DIM + _kc, S + (bufo) + ((ksh) * 8192) + 4096 + (wid << 9)); \
} while (0)

#define STAGE_B(tile, ksh, bufo) do {                                                   \
    int _kc = ((tile) << 6) + ((ksh) << 5) + gcol;        /* FULL k into wt */          \
    const unsigned short* _w0 = wt + (size_t)(n0 + srow) * KTOT + _kc;                  \
    GLD16(_w0, S + (bufo) + 16384 + ((ksh) * 8192) + (wid << 9));                       \
    GLD16(_w0 + (size_t)128 * KTOT, S + (bufo) + 16384 + ((ksh) * 8192) + 4096 + (wid << 9)); \
} while (0)

// arowF/brow0 are PRE-multiplied row bases (shorts). mq offset = 64 rows = 2048 shorts.
#define READ_A(mq, ks, bufo) do {                                                       \
    const unsigned short* _ap = S + (bufo) + (ks) * 8192 + arowF + (mq) * 2048 + cofs;  \
    a[0] = *(const short8*)(_ap);                                                       \
    a[1] = *(const short8*)(_ap + 512);                                                 \
    a[2] = *(const short8*)(_ap + 1024);                                                \
    a[3] = *(const short8*)(_ap + 1536);                                                \
} while (0)

#define READ_B(ks, bufo) do {                                                           \
    const unsigned short* _bp = S + (bufo) + 16384 + (ks) * 8192 + brow0 + cofs;        \
    b[0] = *(const short8*)(_bp);                                                       \
    b[1] = *(const short8*)(_bp + 512);                                                 \
    b[2] = *(const short8*)(_bp + 1024);                                                \
    b[3] = *(const short8*)(_bp + 1536);                                                \
} while (0)

#define MFMA16(mq) do {                                                                 \
    _Pragma("unroll") for (int _m = 0; _m < 4; ++_m)                                    \
    _Pragma("unroll") for (int _n = 0; _n < 4; ++_n)                                    \
        acc[(mq) * 4 + _m][_n] =                                                        \
            __builtin_amdgcn_mfma_f32_16x16x32_bf16(a[_m], b[_n], acc[(mq) * 4 + _m][_n], 0, 0, 0); \
} while (0)

// single barrier per phase; sched_barrier pins program order at both edges
#define PH_TOP()  __builtin_amdgcn_s_barrier();                                         \
                  asm volatile("s_waitcnt lgkmcnt(0)" ::: "memory");                    \
                  __builtin_amdgcn_sched_barrier(0);                                    \
                  __builtin_amdgcn_s_setprio(1)
#define PH_BOT()  __builtin_amdgcn_s_setprio(0); __builtin_amdgcn_sched_barrier(0)
#define VMC6()    asm volatile("s_waitcnt vmcnt(6)" ::: "memory")
#define VMC4()    asm volatile("s_waitcnt vmcnt(4)" ::: "memory")
#define VMC0()    asm volatile("s_waitcnt vmcnt(0)" ::: "memory")
#define BUF1 32768

__global__ __launch_bounds__(512, 2) void k_gemm(const unsigned short* __restrict__ xb,
                                                 const unsigned short* __restrict__ meanb,
                                                 const unsigned short* __restrict__ wt,
                                                 const float* __restrict__ bias,
                                                 float* __restrict__ outf,
                                                 unsigned short* __restrict__ xbn,
                                                 int wf32, int wbf16) {
    extern __shared__ unsigned short S[];  // 131072 B
    int tid = threadIdx.x;
    int lane = tid & 63, wid = tid >> 6;

    // bijective XCD swizzle (m204)
    int orig = blockIdx.x;
    int xcd = orig & 7, tix = orig >> 3;
    const int q = NWG_GEMM >> 3, r = NWG_GEMM & 7;  // 29, 4
    int wgid = (xcd < r ? xcd * (q + 1) : r * (q + 1) + (xcd - r) * q) + tix;
    int bn = wgid & 1, bm = wgid >> 1;
    int m0 = bm * 256, n0 = bn * 256;
    int wm = wid >> 2, wn = wid & 3;

    // ds_read-side constants; swizzle f depends only on r15 (invariant under +16k rows)
    int r15 = lane & 15, c4 = lane >> 4;
    int f = (r15 + (r15 >> 2)) & 3;
    int cofs = ((c4 ^ f) << 3);              // shorts
    int arowF = (wm * 128 + r15) * 32;       // row base, shorts
    int brow0 = (wn * 64 + r15) * 32;

    // stage-side constants (f_t invariant under +128 rows)
    int srow = tid >> 2;                     // 0..127
    int f_t = (srow + (srow >> 2)) & 3;
    int gcol = (((tid & 3) ^ f_t) << 3);     // pre-swizzled global source col (elements)

    short8 a[4], b[4];
    f32x4 acc[8][4] = {};

    // prologue: tile0 all 4 slots -> buf0 (loads 1-8); tile1 k0 slots -> buf1 (9-12).
    // VMC4 -> thru load 8: tile0 fully landed.
    STAGE_B(0, 0, 0); STAGE_A(0, 0, 0); STAGE_B(0, 1, 0); STAGE_A(0, 1, 0);
    STAGE_B(1, 0, BUF1); STAGE_A(1, 0, BUF1);
    VMC4();
    __builtin_amdgcn_s_barrier();

    for (int it = 0; it < NT / 2; ++it) {
        int t1 = 2 * it + 1, t2 = 2 * it + 2, t3 = 2 * it + 3;  // t1 < NT always
        // ph1: read b0-k0 mq0 + B | stage B(t1,k1,b1)
        READ_A(0, 0, 0); READ_B(0, 0);
        STAGE_B(t1, 1, BUF1);
        PH_TOP(); MFMA16(0); PH_BOT();
        // ph2: read b0-k0 mq1 | VMC6 (-> thru ph6 of prev iter)
        READ_A(1, 0, 0);
        VMC6();
        PH_TOP(); MFMA16(1); PH_BOT();
        // ph3: read b0-k1 mq0 + B | stage A(t1,k1,b1) then B(t2,k0,b0)
        READ_A(0, 1, 0); READ_B(1, 0);
        STAGE_A(t1, 1, BUF1);
        if (t2 < NT) STAGE_B(t2, 0, 0);
        PH_TOP(); MFMA16(0); PH_BOT();
        // ph4: read b0-k1 mq1 | stage A(t2,k0,b0) | VMC6 (-> thru ph1 this iter)
        READ_A(1, 1, 0);
        if (t2 < NT) { STAGE_A(t2, 0, 0); VMC6(); } else { VMC0(); }
        PH_TOP(); MFMA16(1); PH_BOT();
        // ph5: read b1-k0 mq0 + B | stage B(t2,k1,b0)
        READ_A(0, 0, BUF1); READ_B(0, BUF1);
        if (t2 < NT) STAGE_B(t2, 1, 0);
        PH_TOP(); MFMA16(0); PH_BOT();
        // ph6: read b1-k0 mq1 | stage A(t2,k1,b0) | VMC6 (-> thru ph3 this iter)
        READ_A(1, 0, BUF1);
        if (t2 < NT) { STAGE_A(t2, 1, 0); VMC6(); } else { VMC0(); }
        PH_TOP(); MFMA16(1); PH_BOT();
        // ph7: read b1-k1 mq0 + B | stage B(t3,k0,b1)
        READ_A(0, 1, BUF1); READ_B(1, BUF1);
        if (t3 < NT) STAGE_B(t3, 0, BUF1);
        PH_TOP(); MFMA16(0); PH_BOT();
        // ph8: read b1-k1 mq1 | stage A(t3,k0,b1) | VMC6 (-> thru ph5 this iter)
        READ_A(1, 1, BUF1);
        if (t3 < NT) { STAGE_A(t3, 0, BUF1); VMC6(); } else { VMC0(); }
        PH_TOP(); MFMA16(1); PH_BOT();
    }
    VMC0();

    // epilogue: bias + relu + bf16 residual (xb is also A part 0 -> cache-hot)
    #pragma unroll
    for (int mm = 0; mm < 8; ++mm) {
        int rowoff = ((mm >> 2) << 6) + ((mm & 3) << 4);
        #pragma unroll
        for (int j = 0; j < 4; ++j) {
            int row = m0 + wm * 128 + rowoff + c4 * 4 + j;
            if (row >= N_NODES) continue;
            #pragma unroll
            for (int n = 0; n < 4; ++n) {
                int col = n0 + wn * 64 + n * 16 + r15;
                float v = acc[mm][n][j] + bias[col];
                v = fmaxf(v, 0.0f) + bf2f(xb[(size_t)row * DIM + col]);
                if (wf32)  outf[(size_t)row * DIM + col] = v;
                if (wbf16) xbn[(size_t)row * DIM + col] = f2bf(v);
            }
        }
    }
}

extern "C" void kernel_launch(void* const* d_in, const int* in_sizes, int n_in,
                              void* d_out, int out_size, void* d_ws, size_t ws_size,
                              hipStream_t stream) {
    const int* xidx   = (const int*)d_in[0];
    const int* eidx   = (const int*)d_in[1];
    const int* etype  = (const int*)d_in[2];
    const float* emb  = (const float*)d_in[3];
    const float* Wl[3]    = {(const float*)d_in[4], (const float*)d_in[7], (const float*)d_in[10]};
    const float* rootl[3] = {(const float*)d_in[5], (const float*)d_in[8], (const float*)d_in[11]};
    const float* bl[3]    = {(const float*)d_in[6], (const float*)d_in[9], (const float*)d_in[12]};
    const int* esrc = eidx;
    const int* edst = eidx + N_EDGES;

    char* ws = (char*)d_ws;
    size_t off = 0;
    auto take = [&](size_t bytes) { char* p = ws + off; off = (off + bytes + 255) & ~(size_t)255; return p; };
    unsigned short* xb0  = (unsigned short*)take((size_t)N_NODES * DIM * 2);
    unsigned short* xb1  = (unsigned short*)take((size_t)N_NODES * DIM * 2);
    unsigned short* meanb= (unsigned short*)take((size_t)NREL * N_NODES * DIM * 2);
    unsigned short* wcat = (unsigned short*)take((size_t)3 * DIM * KTOT * 2);
    int* hist    = (int*)take((size_t)NSEG * 4);
    int* offsets = (int*)take((size_t)(NSEG + 1) * 4);
    int* cursor  = (int*)take((size_t)NSEG * 4);
    int* bsums   = (int*)take(64 * 4);
    int* ssrc    = (int*)take((size_t)N_EDGES * 4);

    hipMemsetAsync(hist, 0, (size_t)NSEG * 4, stream);
    hipMemsetAsync(cursor, 0, (size_t)NSEG * 4, stream);
    for (int l = 0; l < 3; l++) {
        k_wcat<<<(DIM * KTOT + 255) / 256, 256, 0, stream>>>(Wl[l], rootl[l],
                                                             wcat + (size_t)l * DIM * KTOT);
    }
    k_embed<<<(N_NODES + 3) / 4, 256, 0, stream>>>(xidx, emb, xb0);
    k_hist<<<(N_EDGES + 255) / 256, 256, 0, stream>>>(etype, edst, hist);
    k_scan1<<<(NSEG + 2047) / 2048, 256, 0, stream>>>(hist, offsets, bsums);
    k_scan2<<<1, 64, 0, stream>>>(bsums, (NSEG + 2047) / 2048);
    k_scan3<<<(NSEG + 2047) / 2048, 256, 0, stream>>>(bsums, offsets);
    k_scatter<<<(N_EDGES + 255) / 256, 256, 0, stream>>>(etype, esrc, edst, offsets, cursor, ssrc);

    unsigned short* xb_cur = xb0;
    unsigned short* xb_nxt = xb1;
    for (int l = 0; l < 3; l++) {
        k_agg<<<N_NODES, 256, 0, stream>>>(xb_cur, ssrc, offsets, meanb);
        int last = (l == 2);
        k_gemm<<<NWG_GEMM, 512, 131072, stream>>>(xb_cur, meanb, wcat + (size_t)l * DIM * KTOT,
                                                  bl[l], (float*)d_out, xb_nxt,
                                                  last ? 1 : 0, last ? 0 : 1);
        unsigned short* t = xb_cur; xb_cur = xb_nxt; xb_nxt = t;
    }
}